// Round 4
// baseline (130.047 us; speedup 1.0000x reference)
//
#include <hip/hip_runtime.h>

// SIAF forward, two fused MFMA GEMMs, zero h-transpose:
//   GEMM1 row order is PERMUTED so that each lane's C-layout accs (rows q*4+reg of
//   tiles 2w, 2w+1) are exactly the GEMM2 B-frag rows q*8+j of k-window w.
//   Bias b1 is the MFMA C-init (not a weight column), so rows with l<32 have an
//   all-zero upper k-half -> mt<4 skips half its GEMM1 MFMAs + w1 bytes.
//   w1/b1 pre-scaled by YSCALE so tanh(y) = 1 - 2*rcp(exp2(y')+1) (native v_exp).
// LDS: only xz[4][32][64] fp32 (32 KB/block): x staged coalesced, z in-place,
// stored coalesced. No barriers anywhere (all wave-private).

#define DIMS 64

typedef __attribute__((ext_vector_type(8))) short short8;
typedef __attribute__((ext_vector_type(4))) float f32x4;
typedef __attribute__((ext_vector_type(4))) unsigned int uint4v;
typedef unsigned short ushort_t;
typedef unsigned int uint_t;

#if __has_builtin(__builtin_amdgcn_exp2f)
#define YSCALE 2.8853900817779268f      /* 2*log2(e): exp(2y) = exp2(YSCALE*y) */
#define EXPY(x) __builtin_amdgcn_exp2f(x)
#else
#define YSCALE 2.0f
#define EXPY(x) __expf(x)
#endif

__device__ __forceinline__ uint_t pk2bf(float a, float b) {
#if __has_builtin(__builtin_amdgcn_cvt_pk_bf16_f32)
    typedef __attribute__((ext_vector_type(2))) __bf16 bf16x2;
    bf16x2 r = __builtin_amdgcn_cvt_pk_bf16_f32(a, b);
    return __builtin_bit_cast(uint_t, r);
#else
    uint_t ua = __float_as_uint(a); ua += 0x7FFFu + ((ua >> 16) & 1u);
    uint_t ub = __float_as_uint(b); ub += 0x7FFFu + ((ub >> 16) & 1u);
    return (ub & 0xFFFF0000u) | (ua >> 16);
#endif
}

__device__ __forceinline__ ushort_t f2bf(float f) {
    uint_t u = __float_as_uint(f);
    u += 0x7FFFu + ((u >> 16) & 1u);
    return (ushort_t)(u >> 16);
}

// ws: w1b us[512*64] | w2full us[128*64] | b1f f[512] | b2f f[128]
#define W2F_OFF (512 * 64)
#define FREG_OFF (512 * 64 + 128 * 64)
#define PREP_N (512 * 64 + 128 * 64 + 512 + 128)

// logical row L for physical GEMM1 row p: window w=p>>5, tile parity e=(p>>4)&1,
// n=p&15 -> L = w*32 + (n>>2)*8 + e*4 + (n&3).  (l = L>>3, h = L&7)
__device__ __forceinline__ int logrow(int p) {
    int n = p & 15;
    return (p >> 5) * 32 + (n >> 2) * 8 + ((p >> 4) & 1) * 4 + (n & 3);
}

__global__ void siaf_prep(const float* __restrict__ W1, const float* __restrict__ b1,
                          const float* __restrict__ W2, const float* __restrict__ b2,
                          ushort_t* __restrict__ ws_u) {
    ushort_t* w1b    = ws_u;
    ushort_t* w2full = ws_u + W2F_OFF;
    float*    fb     = (float*)(ws_u + FREG_OFF);
    int i = blockIdx.x * 256 + threadIdx.x;
    if (i < 512 * 64) {
        int k = i & 63, p = i >> 6;
        int L = logrow(p), l = L >> 3, h = L & 7;
        float v = 0.0f;
        if (l < 63 && k <= l) v = W1[(l * 8 + h) * 63 + k] * YSCALE;
        w1b[i] = f2bf(v);
    } else if (i < FREG_OFF) {
        int j = i - W2F_OFF;
        int kl = j & 63, r = j >> 6, l = r >> 1, o = r & 1;
        float v = 0.0f;
        if (l < 63 && (kl >> 3) == (l & 7)) v = W2[(l * 2 + o) * 8 + (kl & 7)];
        w2full[j] = f2bf(v);
    } else if (i < FREG_OFF + 512) {
        int p = i - FREG_OFF;
        int L = logrow(p), l = L >> 3, h = L & 7;
        fb[p] = (l < 63) ? b1[l * 8 + h] * YSCALE : 0.0f;
    } else if (i < PREP_N) {
        int j = i - (FREG_OFF + 512);
        int l = j >> 1, o = j & 1;
        fb[512 + j] = (l < 63) ? b2[l * 2 + o] : 0.0f;
    }
}

__device__ __forceinline__ float th(float t) {
    // t = YSCALE*y ; tanh(y) = 1 - 2/(exp2(t)+1)
    float e = EXPY(t);
    float r = __builtin_amdgcn_rcpf(e + 1.0f);
    return fmaf(-2.0f, r, 1.0f);
}

__global__ __launch_bounds__(256, 5) void siaf_mfma(
        const float* __restrict__ x, const float* __restrict__ ip,
        const ushort_t* __restrict__ ws_u, float* __restrict__ out, int nB) {
    const ushort_t* w1b    = ws_u;
    const ushort_t* w2full = ws_u + W2F_OFF;
    const float*    b1f    = (const float*)(ws_u + FREG_OFF);
    const float*    b2f    = b1f + 512;

    __shared__ float xz[4][32 * 64];   // [wave][s_loc][64], 16B-chunk XOR swizzle

    const int tid  = threadIdx.x;
    const int wv   = tid >> 6, lane = tid & 63;
    const int s16  = lane & 15, quad = lane >> 4;
    const int sbase = blockIdx.x * 128 + wv * 32;

    float* xzw = xz[wv];

    // ---- phase 1: coalesced global -> LDS (1KB per wave instruction) ----
    #pragma unroll
    for (int g = 0; g < 8; ++g) {
        const float4 v = ((const float4*)(x + (size_t)(sbase + 4 * g) * DIMS))[lane];
        const int s_loc = 4 * g + quad;
        const int chunk = (lane & 15) ^ (s_loc & 15);
        *(float4*)(xzw + s_loc * 64 + chunk * 4) = v;
    }

    const float ip0 = ip[0], ip1 = ip[1];

    // ---- phase 2: x B-frags (bf16) from LDS ----
    short8 bfr[2][2];
    float lsum[2] = {0.0f, 0.0f};
    #pragma unroll
    for (int st = 0; st < 2; ++st) {
        const int s_loc = st * 16 + s16;
        #pragma unroll
        for (int kh = 0; kh < 2; ++kh) {
            const int c0 = kh * 8 + quad * 2;
            float4 va = *(const float4*)(xzw + s_loc * 64 + ((c0 ^ s16) & 15) * 4);
            float4 vb = *(const float4*)(xzw + s_loc * 64 + (((c0 + 1) ^ s16) & 15) * 4);
            uint4v u = {pk2bf(va.x, va.y), pk2bf(va.z, va.w),
                        pk2bf(vb.x, vb.y), pk2bf(vb.z, vb.w)};
            bfr[st][kh] = __builtin_bit_cast(short8, u);
        }
    }

    for (int mt = 0; mt < 8; ++mt) {
        const ushort_t* w2p = w2full + (mt * 16 + s16) * 64 + quad * 8;
        f32x4 acc2[2] = {{0.f, 0.f, 0.f, 0.f}, {0.f, 0.f, 0.f, 0.f}};

        #pragma unroll
        for (int half = 0; half < 2; ++half) {
            const int p0 = mt * 4 + half * 2;       // physical tile pair (e=0, e=1)
            const ushort_t* w1p0 = w1b + (p0 * 16 + s16) * 64 + quad * 8;
            const ushort_t* w1p1 = w1p0 + 1024;     // tile p0+1
            const short8 a00 = *(const short8*)w1p0;
            const short8 a10 = *(const short8*)w1p1;
            const float4 bi0 = *(const float4*)(b1f + p0 * 16 + quad * 4);
            const float4 bi1 = *(const float4*)(b1f + (p0 + 1) * 16 + quad * 4);
            const short8 c2 = *(const short8*)(w2p + half * 32);
            short8 a01, a11;
            if (mt >= 4) {                          // rows with l>=32: upper k-half nonzero
                a01 = *(const short8*)(w1p0 + 32);
                a11 = *(const short8*)(w1p1 + 32);
            }
            #pragma unroll
            for (int st = 0; st < 2; ++st) {
                f32x4 aE = {bi0.x, bi0.y, bi0.z, bi0.w};
                f32x4 aO = {bi1.x, bi1.y, bi1.z, bi1.w};
                aE = __builtin_amdgcn_mfma_f32_16x16x32_bf16(a00, bfr[st][0], aE, 0, 0, 0);
                aO = __builtin_amdgcn_mfma_f32_16x16x32_bf16(a10, bfr[st][0], aO, 0, 0, 0);
                if (mt >= 4) {
                    aE = __builtin_amdgcn_mfma_f32_16x16x32_bf16(a01, bfr[st][1], aE, 0, 0, 0);
                    aO = __builtin_amdgcn_mfma_f32_16x16x32_bf16(a11, bfr[st][1], aO, 0, 0, 0);
                }
                // lane's own accs ARE its GEMM2 B-frag (row permutation in prep)
                uint4v hh = {pk2bf(th(aE[0]), th(aE[1])), pk2bf(th(aE[2]), th(aE[3])),
                             pk2bf(th(aO[0]), th(aO[1])), pk2bf(th(aO[2]), th(aO[3]))};
                const short8 hfr = __builtin_bit_cast(short8, hh);
                acc2[st] = __builtin_amdgcn_mfma_f32_16x16x32_bf16(c2, hfr, acc2[st], 0, 0, 0);
            }
        }

        // ---- epilogue for l = mt*8 .. mt*8+7: z in-place in LDS ----
        const int l0 = mt * 8 + quad * 2;
        const float4 b2v = *(const float4*)(b2f + l0 * 2);
        const bool pad = (l0 == 62);                // l=63 slot is padding -> handles d=0
        #pragma unroll
        for (int st = 0; st < 2; ++st) {
            const int s_loc = st * 16 + s16;
            float mu0 = acc2[st][0] + b2v.x, al0 = acc2[st][1] + b2v.y;
            float mu1 = acc2[st][2] + b2v.z, al1 = acc2[st][3] + b2v.w;
            const int d1 = l0 + 1;
            float* p1 = xzw + s_loc * 64 + (((((d1 >> 2) ^ s16) & 15) << 2) | (d1 & 3));
            *p1 = fmaf(*p1, __expf(al0), mu0);
            lsum[st] += al0;
            const float alB = pad ? ip1 : al1;
            const float muB = pad ? ip0 : mu1;
            const int d2 = pad ? 0 : (l0 + 2);
            float* p2 = xzw + s_loc * 64 + (((((d2 >> 2) ^ s16) & 15) << 2) | (d2 & 3));
            *p2 = fmaf(*p2, __expf(alB), muB);
            lsum[st] += alB;
        }
    }

    // ---- phase 4: coalesced LDS -> global z store ----
    #pragma unroll
    for (int g = 0; g < 8; ++g) {
        const int s_loc = 4 * g + quad;
        const int chunk = (lane & 15) ^ (s_loc & 15);
        const float4 v = *(const float4*)(xzw + s_loc * 64 + chunk * 4);
        ((float4*)(out + (size_t)(sbase + 4 * g) * DIMS))[lane] = v;
    }

    // ---- log_det: sum the 4 quad-partials per sample ----
    #pragma unroll
    for (int st = 0; st < 2; ++st) {
        float v = lsum[st];
        int r1 = __builtin_amdgcn_ds_swizzle(__float_as_int(v), 0x401F);  // xor 16
        v += __int_as_float(r1);
        int r2 = __builtin_amdgcn_ds_bpermute((lane ^ 32) << 2, __float_as_int(v));
        v += __int_as_float(r2);
        if (quad == 0)
            out[(size_t)nB * DIMS + sbase + st * 16 + s16] = v;
    }
}

extern "C" void kernel_launch(void* const* d_in, const int* in_sizes, int n_in,
                              void* d_out, int out_size, void* d_ws, size_t ws_size,
                              hipStream_t stream) {
    const float* x  = (const float*)d_in[0];
    const float* ip = (const float*)d_in[1];
    const float* W1 = (const float*)d_in[2];
    const float* b1 = (const float*)d_in[3];
    const float* W2 = (const float*)d_in[4];
    const float* b2 = (const float*)d_in[5];
    ushort_t* ws = (ushort_t*)d_ws;
    float* out = (float*)d_out;

    const int nB = in_sizes[0] / DIMS;      // 131072

    siaf_prep<<<(PREP_N + 255) / 256, 256, 0, stream>>>(W1, b1, W2, b2, ws);
    siaf_mfma<<<nB / 128, 256, 0, stream>>>(x, ip, ws, out, nB);
}